// Round 4
// baseline (24.578 us; speedup 1.0000x reference)
//
#include <hip/hip_runtime.h>

// out[b,s,:] = qz[b,s-24,:] + qz[b,s+24,:]   (terms dropped out of range)
// attn_mat == identity, period_mat == +/-24 shift. Pure memory-bound shift-add.
// Traffic floor: 64 MiB read + 64 MiB write beyond L2 per replay.
//
// R4: revert R2's non-temporal store. NT (no-allocate) forces every output
// line to drain to HBM and bypasses L3 write-back absorption; the 128 MB
// working set is L3-resident across graph replays, and the 6.9 TB/s fill
// kernels use regular stores. Keep unroll-4 + 4096 blocks (neutral in R3,
// harmless).

constexpr int SEQ    = 2048;
constexpr int PERIOD = 24;
constexpr int DV     = 1024 / 4;             // float4s per row = 256
constexpr int TOTALV = 8 * SEQ * DV;         // 4,194,304 float4 elements
constexpr int BLOCKS  = 4096;
constexpr int THREADS = 256;
constexpr int SWEEP   = BLOCKS * THREADS;    // 1,048,576 -> exactly 4 sweeps
constexpr int NSWEEP  = TOTALV / SWEEP;      // 4 (exact)

typedef float f32x4 __attribute__((ext_vector_type(4)));

__global__ __launch_bounds__(256, 8) void ptperiod_shift_add(
        const f32x4* __restrict__ qz, f32x4* __restrict__ out) {
    const int base = blockIdx.x * THREADS + threadIdx.x;
#pragma unroll
    for (int k = 0; k < NSWEEP; ++k) {
        const int i = base + k * SWEEP;
        const int s = (i >> 8) & (SEQ - 1);  // seq position (row = i>>8, SEQ pow2)
        f32x4 r = (f32x4){0.f, 0.f, 0.f, 0.f};
        if (s >= PERIOD)       r += qz[i - PERIOD * DV];  // wave-uniform branch
        if (s < SEQ - PERIOD)  r += qz[i + PERIOD * DV];  // wave-uniform branch
        out[i] = r;                                       // plain write-back store
    }
}

extern "C" void kernel_launch(void* const* d_in, const int* in_sizes, int n_in,
                              void* d_out, int out_size, void* d_ws, size_t ws_size,
                              hipStream_t stream) {
    const f32x4* qz  = (const f32x4*)d_in[0];   // [8,2048,1024] f32
    f32x4*       out = (f32x4*)d_out;           // [8,2048,1024] f32

    hipLaunchKernelGGL(ptperiod_shift_add, dim3(BLOCKS), dim3(THREADS), 0, stream,
                       qz, out);
}